// Round 19
// baseline (162.388 us; speedup 1.0000x reference)
//
#include <hip/hip_runtime.h>
#include <hip/hip_bf16.h>
#include <stdint.h>

#define B_ 4
#define C_ 256
#define N_ 4096
#define D_ 32

typedef __bf16 bf16_t;
typedef __bf16 bf16x8_t __attribute__((ext_vector_type(8)));
typedef float  f32x4    __attribute__((ext_vector_type(4)));

// ---------------------------------------------------------------------------
// cast W (wq|wk|wv) -> Wb bf16 [320][256]
// ---------------------------------------------------------------------------
__global__ __launch_bounds__(256) void cast_w_kernel(
    const float* __restrict__ wq, const float* __restrict__ wk,
    const float* __restrict__ wv, bf16_t* __restrict__ Wb)
{
  const int gr = blockIdx.x;
  const int t  = threadIdx.x;
  float v;
  if (gr < 32)      v = wq[gr * C_ + t];
  else if (gr < 64) v = wk[(gr - 32) * C_ + t];
  else              v = wv[(gr - 64) * C_ + t];
  Wb[gr * C_ + t] = (bf16_t)v;
}

// ---------------------------------------------------------------------------
// Projection GEMM with fused x-transpose (R12/R15 proven version).
// ---------------------------------------------------------------------------
__global__ __launch_bounds__(256) void proj_kernel(
    const float* __restrict__ x, const bf16_t* __restrict__ Wb,
    const float* __restrict__ bq, const float* __restrict__ bk,
    const float* __restrict__ bv,
    bf16_t* __restrict__ Qh, bf16_t* __restrict__ Kh, bf16_t* __restrict__ Vh)
{
  __shared__ float xs[64][65];
  const int bi = blockIdx.x;
  const int b  = bi & 3;
  const int n0 = (bi >> 2) * 64;
  const int t = threadIdx.x, w = t >> 6, lane = t & 63;
  const int l4 = lane >> 4, lm = lane & 15;

  const f32x4 z4 = {0.f, 0.f, 0.f, 0.f};
  f32x4 acc[5][4];
#pragma unroll
  for (int rt = 0; rt < 5; ++rt)
#pragma unroll
    for (int ct = 0; ct < 4; ++ct) acc[rt][ct] = z4;

  const int lr = t >> 2;
  const int lc = (t & 3) * 16;

#pragma unroll 1
  for (int k0 = 0; k0 < C_; k0 += 64) {
    __syncthreads();
#pragma unroll
    for (int i = 0; i < 4; ++i) {
      const f32x4 v = *(const f32x4*)(x + ((size_t)(b * C_ + k0 + lr)) * N_ + n0 + lc + i * 4);
      xs[lr][lc + i * 4 + 0] = v[0];
      xs[lr][lc + i * 4 + 1] = v[1];
      xs[lr][lc + i * 4 + 2] = v[2];
      xs[lr][lc + i * 4 + 3] = v[3];
    }
    __syncthreads();

    bf16x8_t af[5][2], bfr[4][2];
#pragma unroll
    for (int rt = 0; rt < 5; ++rt)
#pragma unroll
      for (int kc = 0; kc < 2; ++kc)
        af[rt][kc] = *(const bf16x8_t*)(Wb + (size_t)(w * 80 + rt * 16 + lm) * C_ + k0 + kc * 32 + l4 * 8);
#pragma unroll
    for (int ct = 0; ct < 4; ++ct)
#pragma unroll
      for (int kc = 0; kc < 2; ++kc) {
        bf16_t tmp[8];
#pragma unroll
        for (int j = 0; j < 8; ++j)
          tmp[j] = (bf16_t)xs[kc * 32 + l4 * 8 + j][ct * 16 + lm];
        bfr[ct][kc] = *(bf16x8_t*)tmp;
      }
#pragma unroll
    for (int rt = 0; rt < 5; ++rt)
#pragma unroll
      for (int ct = 0; ct < 4; ++ct)
#pragma unroll
        for (int kc = 0; kc < 2; ++kc)
          acc[rt][ct] = __builtin_amdgcn_mfma_f32_16x16x32_bf16(af[rt][kc], bfr[ct][kc], acc[rt][ct], 0, 0, 0);
  }

#pragma unroll
  for (int rt = 0; rt < 5; ++rt)
#pragma unroll
    for (int r = 0; r < 4; ++r) {
      const int gr = w * 80 + rt * 16 + 4 * l4 + r;
      const float bias = (gr < 32) ? bq[gr] : (gr < 64) ? bk[gr - 32] : bv[gr - 64];
#pragma unroll
      for (int ct = 0; ct < 4; ++ct) {
        const int n = n0 + ct * 16 + lm;
        float v = acc[rt][ct][r] + bias;
        if (gr < 32) {
          v *= 1.44269504088896f;
          Qh[((size_t)(b * N_ + n)) * D_ + gr] = (bf16_t)v;
        } else if (gr < 64) {
          Kh[((size_t)(b * N_ + n)) * D_ + (gr - 32)] = (bf16_t)v;
        } else {
          Vh[((size_t)(b * C_ + (gr - 64))) * N_ + n] = (bf16_t)v;
        }
      }
    }
}

// ---------------------------------------------------------------------------
// Flash attention, REGISTER-RESIDENT P (R17-proven kperm), zero main-loop
// barriers, REBALANCED partition: grid 512 (q-tile 32), 8 waves =
// 2 ch-halves (cg: 128 ch) x 4 key-quarters (ks: 1024 keys).
//  - S/exp2 duplication 4x -> 2x (R18's VALU tax halved)
//  - pb fragment feeds 8 PV MFMAs (was 4)
//  - acc = 128ch x 32q = 64 VGPRs (no spill)
// Epilogue: ks=1..3 export acc via Ax (one barrier), ks=0 combines + stores.
// ---------------------------------------------------------------------------
__global__ __launch_bounds__(512, 2) void attn_kernel(
    const bf16_t* __restrict__ Qh, const bf16_t* __restrict__ Kh,
    const bf16_t* __restrict__ Vh, const float* __restrict__ x,
    const float* __restrict__ gamma, float* __restrict__ out)
{
  __shared__ float Ax[3][2][32][132];   // 101 KB: [ks-1][cg][q][ch-local pad 132]
  __shared__ float Lx[32][8];           // 1 KB:  [q][wave]

  const int bi = blockIdx.x;
  const int xcd = bi & 7, slot = bi >> 3;
  const int b  = xcd >> 1;                 // 2 XCDs per batch -> K,V,Q L2-resident
  const int q0 = ((xcd & 1) * 64 + slot) * 32;

  const int t = threadIdx.x, w = t >> 6, lane = t & 63;
  const int l4 = lane >> 4, lm = lane & 15;
  const int cg = w & 1, ks = w >> 1;

  const f32x4 z4 = {0.f, 0.f, 0.f, 0.f};

  // Q fragments (B-operand): 2 q-subtiles of 16
  bf16x8_t qf[2];
#pragma unroll
  for (int rt = 0; rt < 2; ++rt)
    qf[rt] = *(const bf16x8_t*)(Qh + ((size_t)(b * N_ + q0 + rt * 16 + lm)) * D_ + l4 * 8);

  // K base with PERMUTED rows (R17-proven): A-frag row lm covers key kperm+4mt
  const int kperm = 8 * (lm >> 2) + (lm & 3);
  const bf16_t* kbaseP = Kh + ((size_t)(b * N_ + ks * 1024 + kperm)) * D_ + l4 * 8;
  // V base: wave's 128 channels (cg half), its 1024-key quarter
  const bf16_t* vbase = Vh + ((size_t)(b * C_ + cg * 128 + lm)) * N_ + ks * 1024 + 8 * l4;

  f32x4 acc[8][2];   // [ct][rt] : 128 ch x 32 q, partial over this wave's keys
#pragma unroll
  for (int ct = 0; ct < 8; ++ct)
#pragma unroll
    for (int rt = 0; rt < 2; ++rt) acc[ct][rt] = z4;
  float l_run[2] = {0.f, 0.f};

  // prologue: K and V fragments for group 0
  bf16x8_t kf[2], kfn[2], vf[8], vfn[8];
#pragma unroll
  for (int mt = 0; mt < 2; ++mt)
    kf[mt] = *(const bf16x8_t*)(kbaseP + (size_t)(4 * mt) * D_);
#pragma unroll
  for (int ct = 0; ct < 8; ++ct)
    vf[ct] = *(const bf16x8_t*)(vbase + (size_t)(ct * 16) * N_);

  // main loop: 32 groups of 32 keys; ZERO barriers, ZERO LDS
#pragma unroll 1
  for (int g = 0; g < 32; ++g) {
    const int kon = ((g + 1) * 32) & 1023;

    // prefetch next K
#pragma unroll
    for (int mt = 0; mt < 2; ++mt)
      kfn[mt] = *(const bf16x8_t*)(kbaseP + (size_t)(kon + 4 * mt) * D_);

    // S -> exp2 -> pack (register-resident P, natural key order via kperm)
    bf16x8_t pb[2];
#pragma unroll
    for (int rt = 0; rt < 2; ++rt) {
      const f32x4 S0 = __builtin_amdgcn_mfma_f32_16x16x32_bf16(kf[0], qf[rt], z4, 0, 0, 0);
      const f32x4 S1 = __builtin_amdgcn_mfma_f32_16x16x32_bf16(kf[1], qf[rt], z4, 0, 0, 0);
      float p[8];
#pragma unroll
      for (int r = 0; r < 4; ++r) p[r]     = __builtin_amdgcn_exp2f(S0[r]);
#pragma unroll
      for (int r = 0; r < 4; ++r) p[4 + r] = __builtin_amdgcn_exp2f(S1[r]);
      l_run[rt] += ((p[0] + p[1]) + (p[2] + p[3])) + ((p[4] + p[5]) + (p[6] + p[7]));
      bf16_t tmp[8];
#pragma unroll
      for (int j = 0; j < 8; ++j) tmp[j] = (bf16_t)p[j];
      pb[rt] = *(bf16x8_t*)tmp;
    }

    // prefetch next V
#pragma unroll
    for (int ct = 0; ct < 8; ++ct)
      vfn[ct] = *(const bf16x8_t*)(vbase + (size_t)(ct * 16) * N_ + kon);

    // PV: 16 MFMAs, all operands in registers
#pragma unroll
    for (int ct = 0; ct < 8; ++ct)
#pragma unroll
      for (int rt = 0; rt < 2; ++rt)
        acc[ct][rt] = __builtin_amdgcn_mfma_f32_16x16x32_bf16(vf[ct], pb[rt], acc[ct][rt], 0, 0, 0);

#pragma unroll
    for (int mt = 0; mt < 2; ++mt) kf[mt] = kfn[mt];
#pragma unroll
    for (int ct = 0; ct < 8; ++ct) vf[ct] = vfn[ct];
  }

  // ---- l reduce: lane-local -> per-q -> Lx ----
#pragma unroll
  for (int rt = 0; rt < 2; ++rt) {
    l_run[rt] += __shfl_xor(l_run[rt], 16);
    l_run[rt] += __shfl_xor(l_run[rt], 32);
  }
  if (l4 == 0) {
#pragma unroll
    for (int rt = 0; rt < 2; ++rt) Lx[rt * 16 + lm][w] = l_run[rt];
  }

  // ---- ks=1..3 export acc; ks=0 combines + stores ----
  if (ks > 0) {
#pragma unroll
    for (int ct = 0; ct < 8; ++ct)
#pragma unroll
      for (int rt = 0; rt < 2; ++rt)
        *(f32x4*)&Ax[ks - 1][cg][rt * 16 + lm][ct * 16 + 4 * l4] = acc[ct][rt];
  }
  asm volatile("s_waitcnt lgkmcnt(0)" ::: "memory");
  __builtin_amdgcn_s_barrier();

  if (ks == 0) {
    const float g = gamma[0];
#pragma unroll
    for (int rt = 0; rt < 2; ++rt) {
      const int ql = rt * 16 + lm;
      const float lt = (Lx[ql][cg] + Lx[ql][2 + cg]) + (Lx[ql][4 + cg] + Lx[ql][6 + cg]);
      const float inv = 1.f / lt;
      const int n = q0 + ql;
#pragma unroll
      for (int ct = 0; ct < 8; ++ct) {
        const f32x4 a1 = *(const f32x4*)&Ax[0][cg][ql][ct * 16 + 4 * l4];
        const f32x4 a2 = *(const f32x4*)&Ax[1][cg][ql][ct * 16 + 4 * l4];
        const f32x4 a3 = *(const f32x4*)&Ax[2][cg][ql][ct * 16 + 4 * l4];
#pragma unroll
        for (int r = 0; r < 4; ++r) {
          const int c = cg * 128 + ct * 16 + 4 * l4 + r;
          const size_t idx = ((size_t)(b * C_ + c)) * N_ + n;
          const float s = (acc[ct][rt][r] + a1[r]) + (a2[r] + a3[r]);
          out[idx] = g * (s * inv) + x[idx];
        }
      }
    }
  }
}

extern "C" void kernel_launch(void* const* d_in, const int* in_sizes, int n_in,
                              void* d_out, int out_size, void* d_ws, size_t ws_size,
                              hipStream_t stream) {
  const float* x     = (const float*)d_in[0];
  const float* wq    = (const float*)d_in[1];
  const float* bq    = (const float*)d_in[2];
  const float* wk    = (const float*)d_in[3];
  const float* bk    = (const float*)d_in[4];
  const float* wv    = (const float*)d_in[5];
  const float* bv    = (const float*)d_in[6];
  const float* gamma = (const float*)d_in[7];
  float* out = (float*)d_out;

  bf16_t* Qh = (bf16_t*)d_ws;
  bf16_t* Kh = Qh + (size_t)B_ * N_ * D_;
  bf16_t* Vh = Kh + (size_t)B_ * N_ * D_;
  bf16_t* Wb = Vh + (size_t)B_ * C_ * N_;

  cast_w_kernel<<<320, 256, 0, stream>>>(wq, wk, wv, Wb);
  proj_kernel<<<256, 256, 0, stream>>>(x, Wb, bq, bk, bv, Qh, Kh, Vh);
  attn_kernel<<<512, 512, 0, stream>>>(Qh, Kh, Vh, x, gamma, out);
}

// Round 20
// 93.294 us; speedup vs baseline: 1.7406x; 1.7406x over previous
//
#include <hip/hip_runtime.h>
#include <hip/hip_bf16.h>
#include <stdint.h>

#define B_ 4
#define C_ 256
#define N_ 4096
#define D_ 32
#define KT 512   // keys per outer iteration (8 iters total)

typedef __bf16 bf16_t;
typedef __bf16 bf16x4_t __attribute__((ext_vector_type(4)));
typedef __bf16 bf16x8_t __attribute__((ext_vector_type(8)));
typedef float  f32x4    __attribute__((ext_vector_type(4)));

// ---------------------------------------------------------------------------
// cast W (wq|wk|wv) -> Wb bf16 [320][256]
// ---------------------------------------------------------------------------
__global__ __launch_bounds__(256) void cast_w_kernel(
    const float* __restrict__ wq, const float* __restrict__ wk,
    const float* __restrict__ wv, bf16_t* __restrict__ Wb)
{
  const int gr = blockIdx.x;
  const int t  = threadIdx.x;
  float v;
  if (gr < 32)      v = wq[gr * C_ + t];
  else if (gr < 64) v = wk[(gr - 32) * C_ + t];
  else              v = wv[(gr - 64) * C_ + t];
  Wb[gr * C_ + t] = (bf16_t)v;
}

// ---------------------------------------------------------------------------
// Projection GEMM with FUSED transpose: reads x f32 directly (no xbT pass).
// Per k-tile: stage x[b][k0:+64][n0:+64] f32 in LDS [64][65] (coalesced
// f32x4 row loads; column fragment reads are 2-way max), cvt to bf16 at
// fragment build. grid 256, n-tile 64. Q pre-scaled by log2(e).
// ---------------------------------------------------------------------------
__global__ __launch_bounds__(256) void proj_kernel(
    const float* __restrict__ x, const bf16_t* __restrict__ Wb,
    const float* __restrict__ bq, const float* __restrict__ bk,
    const float* __restrict__ bv,
    bf16_t* __restrict__ Qh, bf16_t* __restrict__ Kh, bf16_t* __restrict__ Vh)
{
  __shared__ float xs[64][65];
  const int bi = blockIdx.x;
  const int b  = bi & 3;
  const int n0 = (bi >> 2) * 64;
  const int t = threadIdx.x, w = t >> 6, lane = t & 63;
  const int l4 = lane >> 4, lm = lane & 15;

  const f32x4 z4 = {0.f, 0.f, 0.f, 0.f};
  f32x4 acc[5][4];
#pragma unroll
  for (int rt = 0; rt < 5; ++rt)
#pragma unroll
    for (int ct = 0; ct < 4; ++ct) acc[rt][ct] = z4;

  const int lr = t >> 2;          // x row within k-tile (0..63)
  const int lc = (t & 3) * 16;    // col base (0,16,32,48)

#pragma unroll 1
  for (int k0 = 0; k0 < C_; k0 += 64) {
    __syncthreads();   // previous tile's readers done
#pragma unroll
    for (int i = 0; i < 4; ++i) {
      const f32x4 v = *(const f32x4*)(x + ((size_t)(b * C_ + k0 + lr)) * N_ + n0 + lc + i * 4);
      xs[lr][lc + i * 4 + 0] = v[0];
      xs[lr][lc + i * 4 + 1] = v[1];
      xs[lr][lc + i * 4 + 2] = v[2];
      xs[lr][lc + i * 4 + 3] = v[3];
    }
    __syncthreads();

    bf16x8_t af[5][2], bfr[4][2];
#pragma unroll
    for (int rt = 0; rt < 5; ++rt)
#pragma unroll
      for (int kc = 0; kc < 2; ++kc)
        af[rt][kc] = *(const bf16x8_t*)(Wb + (size_t)(w * 80 + rt * 16 + lm) * C_ + k0 + kc * 32 + l4 * 8);
#pragma unroll
    for (int ct = 0; ct < 4; ++ct)
#pragma unroll
      for (int kc = 0; kc < 2; ++kc) {
        bf16_t tmp[8];
#pragma unroll
        for (int j = 0; j < 8; ++j)
          tmp[j] = (bf16_t)xs[kc * 32 + l4 * 8 + j][ct * 16 + lm];
        bfr[ct][kc] = *(bf16x8_t*)tmp;
      }
#pragma unroll
    for (int rt = 0; rt < 5; ++rt)
#pragma unroll
      for (int ct = 0; ct < 4; ++ct)
#pragma unroll
        for (int kc = 0; kc < 2; ++kc)
          acc[rt][ct] = __builtin_amdgcn_mfma_f32_16x16x32_bf16(af[rt][kc], bfr[ct][kc], acc[rt][ct], 0, 0, 0);
  }

#pragma unroll
  for (int rt = 0; rt < 5; ++rt)
#pragma unroll
    for (int r = 0; r < 4; ++r) {
      const int gr = w * 80 + rt * 16 + 4 * l4 + r;
      const float bias = (gr < 32) ? bq[gr] : (gr < 64) ? bk[gr - 32] : bv[gr - 64];
#pragma unroll
      for (int ct = 0; ct < 4; ++ct) {
        const int n = n0 + ct * 16 + lm;
        float v = acc[rt][ct][r] + bias;
        if (gr < 32) {
          v *= 1.44269504088896f;
          Qh[((size_t)(b * N_ + n)) * D_ + gr] = (bf16_t)v;
        } else if (gr < 64) {
          Kh[((size_t)(b * N_ + n)) * D_ + (gr - 32)] = (bf16_t)v;
        } else {
          Vh[((size_t)(b * C_ + (gr - 64))) * N_ + n] = (bf16_t)v;
        }
      }
    }
}

// ---------------------------------------------------------------------------
// Flash attention, fixed-reference exp2 softmax, KT=512 (8 iters).
// 8 waves = 8 ch-groups x 32 ch, each spans all 64 q; keys split 8-way
// (wave owns 64 keys/iter). P double-buffered 2x64KB; ONE lgkm-only barrier
// per iter; l lane-local. V/K direct from L2, depth-2 / 1-iter reg prefetch.
// Best-measured configuration of the session (attn ~75.0 us, total ~92.9 us).
// ---------------------------------------------------------------------------
__global__ __launch_bounds__(512, 2) void attn_kernel(
    const bf16_t* __restrict__ Qh, const bf16_t* __restrict__ Kh,
    const bf16_t* __restrict__ Vh, const float* __restrict__ x,
    const float* __restrict__ gamma, float* __restrict__ out)
{
  __shared__ __align__(16) bf16_t Pl[2][64][KT];  // 128 KB double-buffered P
  __shared__ __align__(16) float  Lx[64][12];     // epilogue l exchange

  const int bi = blockIdx.x;
  const int xcd = bi & 7, slot = bi >> 3;
  const int b  = xcd >> 1;                 // 2 XCDs per batch -> K,V,Q L2-resident
  const int q0 = ((xcd & 1) * 32 + slot) * 64;

  const int t = threadIdx.x, w = t >> 6, lane = t & 63;
  const int l4 = lane >> 4, lm = lane & 15;
  const int swz = (lm & 7) << 3;

  const f32x4 z4 = {0.f, 0.f, 0.f, 0.f};

  // Q fragments: 4 q-subtiles of 16 (held whole kernel)
  bf16x8_t qf[4];
#pragma unroll
  for (int rt = 0; rt < 4; ++rt)
    qf[rt] = *(const bf16x8_t*)(Qh + ((size_t)(b * N_ + q0 + rt * 16 + lm)) * D_ + l4 * 8);

  const bf16_t* kbase = Kh + ((size_t)(b * N_ + w * 64 + lm)) * D_ + l4 * 8;
  const bf16_t* vbase = Vh + ((size_t)(b * C_ + w * 32 + lm)) * N_ + l4 * 8;

  f32x4 acc[2][4];   // [ct][rt] : 32 ch x 64 q
#pragma unroll
  for (int ct = 0; ct < 2; ++ct)
#pragma unroll
    for (int rt = 0; rt < 4; ++rt) acc[ct][rt] = z4;
  float l_run[4] = {0.f, 0.f, 0.f, 0.f};   // lane-local partial denominators

  // prologue: K tile 0 (wave's 64-key slice); V fragments for substeps 0/1
  bf16x8_t kf[4], kn[4];
#pragma unroll
  for (int mt = 0; mt < 4; ++mt)
    kf[mt] = *(const bf16x8_t*)(kbase + (size_t)(mt * 16) * D_);
  bf16x8_t vf0[2][2], vf1[2][2];
#pragma unroll
  for (int ct = 0; ct < 2; ++ct)
#pragma unroll
    for (int kc = 0; kc < 2; ++kc) {
      vf0[ct][kc] = *(const bf16x8_t*)(vbase + (size_t)(ct * 16) * N_ + kc * 32);
      vf1[ct][kc] = *(const bf16x8_t*)(vbase + (size_t)(ct * 16) * N_ + 64 + kc * 32);
    }

#pragma unroll 1
  for (int it = 0; it < N_ / KT; ++it) {
    const int buf = it & 1;

    // ---- S: 64 q x this wave's 64 keys ----
    f32x4 S[4][4];
#pragma unroll
    for (int rt = 0; rt < 4; ++rt)
#pragma unroll
      for (int mt = 0; mt < 4; ++mt)
        S[rt][mt] = __builtin_amdgcn_mfma_f32_16x16x32_bf16(kf[mt], qf[rt], z4, 0, 0, 0);

    // prefetch next iter's K slice (in flight across exp2+PV)
    const int k0n = ((it + 1) * KT) & (N_ - 1);
#pragma unroll
    for (int mt = 0; mt < 4; ++mt)
      kn[mt] = *(const bf16x8_t*)(kbase + (size_t)(k0n + mt * 16) * D_);

    // ---- p = exp2(S) (fixed reference 0), P write, local l acc ----
#pragma unroll
    for (int rt = 0; rt < 4; ++rt) {
      const int prow = rt * 16 + lm;
#pragma unroll
      for (int mt = 0; mt < 4; ++mt) {
        const float p0 = __builtin_amdgcn_exp2f(S[rt][mt][0]);
        const float p1 = __builtin_amdgcn_exp2f(S[rt][mt][1]);
        const float p2 = __builtin_amdgcn_exp2f(S[rt][mt][2]);
        const float p3 = __builtin_amdgcn_exp2f(S[rt][mt][3]);
        l_run[rt] += (p0 + p1) + (p2 + p3);
        bf16x4_t w4 = {(bf16_t)p0, (bf16_t)p1, (bf16_t)p2, (bf16_t)p3};
        *(bf16x4_t*)&Pl[buf][prow][(w * 64 + mt * 16 + 4 * l4) ^ swz] = w4;
      }
    }

    asm volatile("s_waitcnt lgkmcnt(0)" ::: "memory");   // P visible; prev reads drained
    __builtin_amdgcn_s_barrier();

    // ---- PV: 8 barrier-free substeps x 64 keys; V depth-2 reg prefetch ----
#pragma unroll
    for (int s4 = 0; s4 < 8; ++s4) {
      bf16x8_t pa[4][2];
#pragma unroll
      for (int rt = 0; rt < 4; ++rt)
#pragma unroll
        for (int kc = 0; kc < 2; ++kc)
          pa[rt][kc] = *(const bf16x8_t*)&Pl[buf][rt * 16 + lm][(s4 * 64 + kc * 32 + l4 * 8) ^ swz];
      const int knx = (it * KT + (s4 + 2) * 64) & (N_ - 1);
      if ((s4 & 1) == 0) {
#pragma unroll
        for (int ct = 0; ct < 2; ++ct)
#pragma unroll
          for (int kc = 0; kc < 2; ++kc)
#pragma unroll
            for (int rt = 0; rt < 4; ++rt)
              acc[ct][rt] = __builtin_amdgcn_mfma_f32_16x16x32_bf16(vf0[ct][kc], pa[rt][kc], acc[ct][rt], 0, 0, 0);
#pragma unroll
        for (int ct = 0; ct < 2; ++ct)
#pragma unroll
          for (int kc = 0; kc < 2; ++kc)
            vf0[ct][kc] = *(const bf16x8_t*)(vbase + (size_t)(ct * 16) * N_ + knx + kc * 32);
      } else {
#pragma unroll
        for (int ct = 0; ct < 2; ++ct)
#pragma unroll
          for (int kc = 0; kc < 2; ++kc)
#pragma unroll
            for (int rt = 0; rt < 4; ++rt)
              acc[ct][rt] = __builtin_amdgcn_mfma_f32_16x16x32_bf16(vf1[ct][kc], pa[rt][kc], acc[ct][rt], 0, 0, 0);
#pragma unroll
        for (int ct = 0; ct < 2; ++ct)
#pragma unroll
          for (int kc = 0; kc < 2; ++kc)
            vf1[ct][kc] = *(const bf16x8_t*)(vbase + (size_t)(ct * 16) * N_ + knx + kc * 32);
      }
    }

#pragma unroll
    for (int mt = 0; mt < 4; ++mt) kf[mt] = kn[mt];
  }

  // ---- epilogue: reduce l (lane-local -> per-q -> cross-wave), then store ----
#pragma unroll
  for (int rt = 0; rt < 4; ++rt) {
    l_run[rt] += __shfl_xor(l_run[rt], 16);
    l_run[rt] += __shfl_xor(l_run[rt], 32);
  }
  if (l4 == 0) {
#pragma unroll
    for (int rt = 0; rt < 4; ++rt) Lx[rt * 16 + lm][w] = l_run[rt];
  }
  asm volatile("s_waitcnt lgkmcnt(0)" ::: "memory");
  __builtin_amdgcn_s_barrier();

  const float g = gamma[0];
#pragma unroll
  for (int rt = 0; rt < 4; ++rt) {
    const f32x4 s0 = *(const f32x4*)&Lx[rt * 16 + lm][0];
    const f32x4 s1 = *(const f32x4*)&Lx[rt * 16 + lm][4];
    const float lt = ((s0[0] + s0[1]) + (s0[2] + s0[3])) + ((s1[0] + s1[1]) + (s1[2] + s1[3]));
    const float inv = 1.f / lt;
    const int n = q0 + rt * 16 + lm;
#pragma unroll
    for (int ct = 0; ct < 2; ++ct) {
#pragma unroll
      for (int r = 0; r < 4; ++r) {
        const int c = w * 32 + ct * 16 + 4 * l4 + r;
        const size_t idx = ((size_t)(b * C_ + c)) * N_ + n;
        out[idx] = g * (acc[ct][rt][r] * inv) + x[idx];
      }
    }
  }
}

extern "C" void kernel_launch(void* const* d_in, const int* in_sizes, int n_in,
                              void* d_out, int out_size, void* d_ws, size_t ws_size,
                              hipStream_t stream) {
  const float* x     = (const float*)d_in[0];
  const float* wq    = (const float*)d_in[1];
  const float* bq    = (const float*)d_in[2];
  const float* wk    = (const float*)d_in[3];
  const float* bk    = (const float*)d_in[4];
  const float* wv    = (const float*)d_in[5];
  const float* bv    = (const float*)d_in[6];
  const float* gamma = (const float*)d_in[7];
  float* out = (float*)d_out;

  // ws: Qh 1MB | Kh 1MB | Vh 8MB | Wb 160KB
  bf16_t* Qh = (bf16_t*)d_ws;
  bf16_t* Kh = Qh + (size_t)B_ * N_ * D_;
  bf16_t* Vh = Kh + (size_t)B_ * N_ * D_;
  bf16_t* Wb = Vh + (size_t)B_ * C_ * N_;

  cast_w_kernel<<<320, 256, 0, stream>>>(wq, wk, wv, Wb);
  proj_kernel<<<256, 256, 0, stream>>>(x, Wb, bq, bk, bv, Qh, Kh, Vh);
  attn_kernel<<<256, 512, 0, stream>>>(Qh, Kh, Vh, x, gamma, out);
}